// Round 12
// baseline (146.395 us; speedup 1.0000x reference)
//
#include <hip/hip_runtime.h>
#include <hip/hip_bf16.h>
#include <hip/hip_fp16.h>
#include <stdint.h>

// Problem constants
#define NBATCH 4
#define SEQ    2048
#define DIM    1024

typedef __attribute__((ext_vector_type(8))) __bf16 bf16x8;
typedef __attribute__((ext_vector_type(4))) float  f32x4;

// Workspace layout (bytes)
#define OFF_XBF   (0ull)                         // 16 MiB
#define OFF_WBF   (16777216ull)                  //  6 MiB  [3072][1024] bf16
#define OFF_Q     (23068672ull)                  // 16 MiB (pre-scaled by 1/32)
#define OFF_K     (39845888ull)                  // 16 MiB
#define OFF_VT    (56623104ull)                  // 16 MiB  V^T per batch [DIM][SEQ]
#define OFF_SC    (73400320ull)                  // 32 MiB fp16 scores
#define OFF_P     (140509184ull)                 // 32 MiB bf16 probs

__device__ __forceinline__ uint16_t f2bf(float f) {
  uint32_t u = __float_as_uint(f);
  u = (u + 0x7fffu + ((u >> 16) & 1u)) >> 16;   // RTN-even
  return (uint16_t)u;
}

// ---------------- fused converts: X (blocks 0..8191), W (blocks 8192..11263) --
__global__ __launch_bounds__(256) void k_convert(const float* __restrict__ X,
                                                 const float* __restrict__ Wq,
                                                 const float* __restrict__ Wk,
                                                 const float* __restrict__ Wv,
                                                 uint16_t* __restrict__ Xbf,
                                                 uint16_t* __restrict__ Wbf) {
  int id = blockIdx.x;
  if (id < 8192) {
    int i = id * 256 + threadIdx.x;
    float4 v = ((const float4*)X)[i];
    ushort4 o;
    o.x = f2bf(v.x); o.y = f2bf(v.y); o.z = f2bf(v.z); o.w = f2bf(v.w);
    ((ushort4*)Xbf)[i] = o;
  } else {
    int j = id - 8192;                    // 0..3071
    int g = j >> 10;
    const float* W = (g == 0) ? Wq : (g == 1) ? Wk : Wv;
    float scale = (g == 0) ? 0.03125f : 1.0f;   // fold 1/sqrt(1024) into W_q
    int i = (j & 1023) * 256 + threadIdx.x;
    float4 v = ((const float4*)W)[i];
    ushort4 o;
    o.x = f2bf(v.x * scale); o.y = f2bf(v.y * scale);
    o.z = f2bf(v.z * scale); o.w = f2bf(v.w * scale);
    ((ushort4*)(Wbf + (size_t)g * 1048576))[i] = o;
  }
}

// ---------------- common helpers ----------------
// LDS rows are 64 bf16 = 128B; XOR swizzle byte ^= (row&7)<<4; inverse applied
// to the global SOURCE slot (global_load_lds writes linearly).

__device__ __forceinline__ void gll16(const void* g, void* l) {
  __builtin_amdgcn_global_load_lds((const __attribute__((address_space(1))) void*)g,
                                   (__attribute__((address_space(3))) void*)l, 16, 0, 0);
}

__device__ __forceinline__ bf16x8 frag_ld(const char* lds, int row, int kbyte) {
  int bo = row * 128 + kbyte;
  bo ^= (row & 7) << 4;
  return *(const bf16x8*)(lds + bo);
}

#define VM_WAIT6() asm volatile("s_waitcnt vmcnt(6)" ::: "memory")
#define VM_WAIT0() asm volatile("s_waitcnt vmcnt(0)" ::: "memory")
#define RAW_BAR()  asm volatile("s_barrier" ::: "memory")

// ---------------- staging helpers ----------------
__device__ __forceinline__ void stage_tile(const uint16_t* __restrict__ g, int ld,
                                           int t, char* lds) {
#pragma unroll
  for (int c = 0; c < 4; ++c) {
    int L = c * 4096 + t * 16;
    int row = L >> 7;
    int slot = (t & 7) ^ (row & 7);
    gll16((const void*)(g + (size_t)row * ld + slot * 8), (void*)(lds + L));
  }
}

__device__ __forceinline__ void stage_btile(const uint16_t* __restrict__ g, int ld,
                                            int t, char* lds) {
#pragma unroll
  for (int c = 0; c < 2; ++c) {
    int L = c * 4096 + t * 16;
    int row = L >> 7;
    int slot = (t & 7) ^ (row & 7);
    gll16((const void*)(g + (size_t)row * ld + slot * 8), (void*)(lds + L));
  }
}

// ---------------- 128x64 half-tile GEMM core: vmcnt(6), 48KB LDS, 3 blk/CU ---
// Ledger (6 loads/thread per tile = A4 + B2, uniform issue order):
//   prologue: stage(0), stage(1)                 -> 12 loads outstanding
//   tile t entry: vmcnt(6) retires exactly stage(t); barrier => LDS visible
//   post-compute barrier => all reads of buf[t&1] done; then stage(t+2).
// Proven correct in k_scores since R8; at 3 blocks/CU the measured effective
// rate (~0.88us/half-K-step/slot ~ 915 TF) beats the 128^2@2blk core (838 TF)
// -> applied to k_qkv and k_pv this round.
__device__ __forceinline__ void gemm_loop_h(const uint16_t* __restrict__ A, int lda,
                                            const uint16_t* __restrict__ Bm, int ldb,
                                            int ksteps, char* lds, f32x4 acc[4][2]) {
  char* lA0 = lds;          char* lA1 = lds + 16384;
  char* lB0 = lds + 32768;  char* lB1 = lds + 40960;
  const int t = threadIdx.x;
  const int lane = t & 63;
  const int wm = (t >> 6) & 1;                  // 64-row strip
  const int wn = t >> 7;                        // 32-col strip (0..1)
  const int frow = lane & 15;
  const int fk16 = (lane >> 4) * 16;

  stage_tile(A, lda, t, lA0); stage_btile(Bm, ldb, t, lB0);
  if (ksteps > 1) { stage_tile(A + 64, lda, t, lA1); stage_btile(Bm + 64, ldb, t, lB1); }

  for (int kt = 0; kt < ksteps; ++kt) {
    if (kt == ksteps - 1) { VM_WAIT0(); } else { VM_WAIT6(); }
    RAW_BAR();
    const char* cA = (kt & 1) ? lA1 : lA0;
    const char* cB = (kt & 1) ? lB1 : lB0;
#pragma unroll
    for (int ki = 0; ki < 2; ++ki) {
      bf16x8 av[4], bv[2];
#pragma unroll
      for (int mi = 0; mi < 4; ++mi)
        av[mi] = frag_ld(cA, wm * 64 + mi * 16 + frow, ki * 64 + fk16);
#pragma unroll
      for (int ni = 0; ni < 2; ++ni)
        bv[ni] = frag_ld(cB, wn * 32 + ni * 16 + frow, ki * 64 + fk16);
      __builtin_amdgcn_s_setprio(1);
#pragma unroll
      for (int mi = 0; mi < 4; ++mi)
#pragma unroll
        for (int ni = 0; ni < 2; ++ni)
          acc[mi][ni] = __builtin_amdgcn_mfma_f32_16x16x32_bf16(av[mi], bv[ni],
                                                                acc[mi][ni], 0, 0, 0);
      __builtin_amdgcn_s_setprio(0);
    }
    RAW_BAR();
    if (kt + 2 < ksteps) {
      stage_tile (A  + (kt + 2) * 64, lda, t, (kt & 1) ? lA1 : lA0);
      stage_btile(Bm + (kt + 2) * 64, ldb, t, (kt & 1) ? lB1 : lB0);
    }
  }
}

// ---------------- QKV projection: fused 8192x3072, 128x64 strips, 3 blk/CU ---
// Grid 3072 = 64 mt x 48 n-strips, m-FASTEST: id mod 8 = mt mod 8 (64 ≡ 0
// mod 8) -> each XCD only touches its m-residue X slice (L2-resident; proven
// R5 vs R4: FETCH 47 vs 200 MB). 4 exact rounds of 768 slots. Each 64-col
// strip lies wholly inside Q, K, or V (1024 % 64 == 0) -> uniform epilogue.
__global__ __launch_bounds__(256) void k_qkv(const uint16_t* __restrict__ Xbf,
                                             const uint16_t* __restrict__ Wbf,
                                             uint16_t* __restrict__ Qb,
                                             uint16_t* __restrict__ Kb,
                                             uint16_t* __restrict__ Vt) {
  __shared__ __align__(16) char lds[49152];
  int id = blockIdx.x;
  const int mt = id & 63, ns = id >> 6;
  const int m0 = mt * 128, n0 = ns * 64;
  const int g = n0 >> 10, ncol = n0 & 1023;

  f32x4 acc[4][2];
#pragma unroll
  for (int i = 0; i < 4; ++i)
#pragma unroll
    for (int j = 0; j < 2; ++j) acc[i][j] = (f32x4){0.f, 0.f, 0.f, 0.f};

  const uint16_t* A  = Xbf + (size_t)m0 * DIM;
  const uint16_t* Bm = Wbf + (size_t)n0 * DIM;  // Wbf as [3072][1024]
  gemm_loop_h(A, DIM, Bm, DIM, DIM / 64, lds, acc);

  const int lane = threadIdx.x & 63;
  const int wm = (threadIdx.x >> 6) & 1, wn = threadIdx.x >> 7;
  const int rbase = wm * 64 + (lane >> 4) * 4;  // C row = (lane>>4)*4 + reg
  const int cbase = wn * 32 + (lane & 15);      // C col = lane&15

  if (g < 2) {
    uint16_t* out = (g == 0) ? Qb : Kb;
#pragma unroll
    for (int mi = 0; mi < 4; ++mi)
#pragma unroll
      for (int ni = 0; ni < 2; ++ni) {
        int c = ncol + cbase + ni * 16;
#pragma unroll
        for (int r = 0; r < 4; ++r) {
          int m = m0 + rbase + mi * 16 + r;
          out[(size_t)m * DIM + c] = f2bf(acc[mi][ni][r]);
        }
      }
  } else {
    // write V transposed: Vt[b][e][s]
    const int b = m0 >> 11, sl = m0 & 2047;
#pragma unroll
    for (int mi = 0; mi < 4; ++mi)
#pragma unroll
      for (int ni = 0; ni < 2; ++ni) {
        int e = ncol + cbase + ni * 16;
        int s = sl + rbase + mi * 16;
        ushort4 o;
        o.x = f2bf(acc[mi][ni][0]); o.y = f2bf(acc[mi][ni][1]);
        o.z = f2bf(acc[mi][ni][2]); o.w = f2bf(acc[mi][ni][3]);
        *(ushort4*)(Vt + ((size_t)b * DIM + e) * SEQ + s) = o;
      }
  }
}

// ---------------- causal scores: Sc = Q K^T, 128x64 half-tile jobs, fp16 -----
// XCD-aware decode: id mod 8 = p = qt-PAIR index {p, 15-p} (pairs sum to 34
// half-jobs -> all 8 XCDs get exactly 136 jobs). Within an XCD, b-major so the
// live Q working set is one batch's panels (~512KB, L2-resident).
__global__ __launch_bounds__(256) void k_scores(const uint16_t* __restrict__ Qb,
                                                const uint16_t* __restrict__ Kb,
                                                __half* __restrict__ Sc) {
  __shared__ __align__(16) char lds[49152];
  int id = blockIdx.x;                // 0..1087
  int p = id & 7;                     // XCD residue = qt-pair
  int w = id >> 3;                    // 0..135
  int b = w / 34;
  int l = w % 34;
  int thr = (p + 1) * 2;
  int qt, hk;
  if (l < thr) { qt = p;      hk = l; }
  else         { qt = 15 - p; hk = l - thr; }
  int kt = hk >> 1, nh = hk & 1;

  f32x4 acc[4][2];
#pragma unroll
  for (int i = 0; i < 4; ++i)
#pragma unroll
    for (int jj = 0; jj < 2; ++jj) acc[i][jj] = (f32x4){0.f, 0.f, 0.f, 0.f};

  const uint16_t* A  = Qb + ((size_t)b * SEQ + qt * 128) * DIM;
  const uint16_t* Bm = Kb + ((size_t)b * SEQ + kt * 128 + nh * 64) * DIM;
  gemm_loop_h(A, DIM, Bm, DIM, DIM / 64, lds, acc);

  const int lane = threadIdx.x & 63;
  const int wm = (threadIdx.x >> 6) & 1, wn = threadIdx.x >> 7;
  const int rbase = qt * 128 + wm * 64 + (lane >> 4) * 4;
  const int cbase = kt * 128 + nh * 64 + wn * 32 + (lane & 15);
  __half* out = Sc + (size_t)b * SEQ * SEQ;
#pragma unroll
  for (int mi = 0; mi < 4; ++mi)
#pragma unroll
    for (int ni = 0; ni < 2; ++ni) {
      int c = cbase + ni * 16;
#pragma unroll
      for (int r = 0; r < 4; ++r)
        out[(size_t)(rbase + mi * 16 + r) * SEQ + c] = __float2half(acc[mi][ni][r]);
    }
}

// ---------------- row softmax: one WAVE per row, fp16 row in registers -------
struct h4 { __half2 a, b; };          // 8 bytes = 4 halves

__global__ __launch_bounds__(256) void k_softmax(const __half* __restrict__ Sc,
                                                 uint16_t* __restrict__ P) {
  int gid = blockIdx.x * 4 + (threadIdx.x >> 6);
  int lane = threadIdx.x & 63;
  int b = gid >> 11, q = gid & 2047;
  const __half* srow = Sc + ((size_t)b * SEQ + q) * SEQ;
  uint16_t* prow = P + ((size_t)b * SEQ + q) * SEQ;
  int nv = q + 1;
  int kpad = ((q >> 7) + 1) << 7;     // PV reads exactly [0, kpad)
  int niter = (kpad + 255) >> 8;      // 256 halves per wave-iter

  float4 v[8];
  const h4* src = (const h4*)srow;
#pragma unroll
  for (int i = 0; i < 8; ++i) {
    if (i < niter) {
      int idx = lane + (i << 6);
      h4 raw = src[idx];
      float2 fa = __half22float2(raw.a), fb = __half22float2(raw.b);
      int k0 = idx << 2;
      float4 x;
      x.x = (k0 + 0 < nv) ? fa.x : -1e38f;
      x.y = (k0 + 1 < nv) ? fa.y : -1e38f;
      x.z = (k0 + 2 < nv) ? fb.x : -1e38f;
      x.w = (k0 + 3 < nv) ? fb.y : -1e38f;
      v[i] = x;
    } else {
      v[i] = make_float4(-1e38f, -1e38f, -1e38f, -1e38f);
    }
  }
  float m = -1e38f;
#pragma unroll
  for (int i = 0; i < 8; ++i)
    m = fmaxf(m, fmaxf(fmaxf(v[i].x, v[i].y), fmaxf(v[i].z, v[i].w)));
#pragma unroll
  for (int o = 32; o > 0; o >>= 1) m = fmaxf(m, __shfl_xor(m, o));

  float s = 0.f;
#pragma unroll
  for (int i = 0; i < 8; ++i) {
    v[i].x = __expf(v[i].x - m); v[i].y = __expf(v[i].y - m);
    v[i].z = __expf(v[i].z - m); v[i].w = __expf(v[i].w - m);
    s += v[i].x + v[i].y + v[i].z + v[i].w;
  }
#pragma unroll
  for (int o = 32; o > 0; o >>= 1) s += __shfl_xor(s, o);
  float inv = 1.0f / s;

  ushort4* dst = (ushort4*)prow;
#pragma unroll
  for (int i = 0; i < 8; ++i) {
    if (i < niter) {
      int idx = lane + (i << 6);
      if ((idx << 2) < kpad) {
        ushort4 o;
        o.x = f2bf(v[i].x * inv); o.y = f2bf(v[i].y * inv);
        o.z = f2bf(v[i].z * inv); o.w = f2bf(v[i].w * inv);
        dst[idx] = o;
      }
    }
  }
}

// ---------------- PV: O = P V, 128x64 half-tile jobs, 3 blk/CU ---------------
// 1024 jobs = 4b x 16qt x 16et-strips. id mod 8 = b*2+parity -> each XCD hosts
// ONE batch's Vt (4MB, L2-resident) and the 16 et-blocks sharing a P panel sit
// on the SAME XCD. Dispatch order: a ascending (slow) with qt = 14-2a+parity
// -> longest K-loops dispatch FIRST (greedy makespan on 768 slots).
__global__ __launch_bounds__(256) void k_pv(const uint16_t* __restrict__ P,
                                            const uint16_t* __restrict__ Vt,
                                            float* __restrict__ O) {
  __shared__ __align__(16) char lds[49152];
  int id = blockIdx.x;                // 0..1023
  int lo = id & 7;
  int b = lo >> 1, parity = lo & 1;
  int w = id >> 3;                    // 0..127 = a*16 + et
  int a = w >> 4, et = w & 15;
  int qt = 14 - 2 * a + parity;       // a=0 -> qt 15/14 (longest first)

  f32x4 acc[4][2];
#pragma unroll
  for (int i = 0; i < 4; ++i)
#pragma unroll
    for (int j = 0; j < 2; ++j) acc[i][j] = (f32x4){0.f, 0.f, 0.f, 0.f};

  const uint16_t* A = P + (size_t)b * SEQ * SEQ + (size_t)qt * 128 * SEQ;
  const uint16_t* Bm = Vt + (size_t)b * DIM * SEQ + (size_t)et * 64 * SEQ;
  gemm_loop_h(A, SEQ, Bm, SEQ, (qt + 1) * 2, lds, acc);

  const int lane = threadIdx.x & 63;
  const int wm = (threadIdx.x >> 6) & 1, wn = threadIdx.x >> 7;
  const int rbase = qt * 128 + wm * 64 + (lane >> 4) * 4;
  const int cbase = et * 64 + wn * 32 + (lane & 15);
  float* out = O + (size_t)b * SEQ * DIM;
#pragma unroll
  for (int mi = 0; mi < 4; ++mi)
#pragma unroll
    for (int ni = 0; ni < 2; ++ni) {
      int c = cbase + ni * 16;
#pragma unroll
      for (int r = 0; r < 4; ++r)
        out[(size_t)(rbase + mi * 16 + r) * DIM + c] = acc[mi][ni][r];
    }
}

extern "C" void kernel_launch(void* const* d_in, const int* in_sizes, int n_in,
                              void* d_out, int out_size, void* d_ws, size_t ws_size,
                              hipStream_t stream) {
  const float* X  = (const float*)d_in[0];
  const float* Wq = (const float*)d_in[1];
  const float* Wk = (const float*)d_in[2];
  const float* Wv = (const float*)d_in[3];
  char* ws = (char*)d_ws;
  uint16_t* Xbf = (uint16_t*)(ws + OFF_XBF);
  uint16_t* Wbf = (uint16_t*)(ws + OFF_WBF);
  uint16_t* Qb  = (uint16_t*)(ws + OFF_Q);
  uint16_t* Kb  = (uint16_t*)(ws + OFF_K);
  uint16_t* Vt  = (uint16_t*)(ws + OFF_VT);
  __half*   Sc  = (__half*)(ws + OFF_SC);
  uint16_t* P   = (uint16_t*)(ws + OFF_P);
  float*    O   = (float*)d_out;

  k_convert<<<11264, 256, 0, stream>>>(X, Wq, Wk, Wv, Xbf, Wbf);
  k_qkv<<<3072, 256, 0, stream>>>(Xbf, Wbf, Qb, Kb, Vt);
  k_scores<<<1088, 256, 0, stream>>>(Qb, Kb, Sc);
  k_softmax<<<2048, 256, 0, stream>>>(Sc, P);
  k_pv<<<1024, 256, 0, stream>>>(P, Vt, O);
}

// Round 13
// 137.954 us; speedup vs baseline: 1.0612x; 1.0612x over previous
//
#include <hip/hip_runtime.h>
#include <hip/hip_bf16.h>
#include <hip/hip_fp16.h>
#include <stdint.h>

// Problem constants
#define NBATCH 4
#define SEQ    2048
#define DIM    1024

typedef __attribute__((ext_vector_type(8))) __bf16 bf16x8;
typedef __attribute__((ext_vector_type(4))) float  f32x4;

// Workspace layout (bytes)
#define OFF_XBF   (0ull)                         // 16 MiB
#define OFF_WBF   (16777216ull)                  //  6 MiB  [3072][1024] bf16
#define OFF_Q     (23068672ull)                  // 16 MiB (pre-scaled by 1/32)
#define OFF_K     (39845888ull)                  // 16 MiB
#define OFF_VT    (56623104ull)                  // 16 MiB  V^T per batch [DIM][SEQ]
#define OFF_SC    (73400320ull)                  // 32 MiB fp16 scores
#define OFF_P     (140509184ull)                 // 32 MiB bf16 probs

__device__ __forceinline__ uint16_t f2bf(float f) {
  uint32_t u = __float_as_uint(f);
  u = (u + 0x7fffu + ((u >> 16) & 1u)) >> 16;   // RTN-even
  return (uint16_t)u;
}

// ---------------- fused converts: X (blocks 0..8191), W (blocks 8192..11263) --
__global__ __launch_bounds__(256) void k_convert(const float* __restrict__ X,
                                                 const float* __restrict__ Wq,
                                                 const float* __restrict__ Wk,
                                                 const float* __restrict__ Wv,
                                                 uint16_t* __restrict__ Xbf,
                                                 uint16_t* __restrict__ Wbf) {
  int id = blockIdx.x;
  if (id < 8192) {
    int i = id * 256 + threadIdx.x;
    float4 v = ((const float4*)X)[i];
    ushort4 o;
    o.x = f2bf(v.x); o.y = f2bf(v.y); o.z = f2bf(v.z); o.w = f2bf(v.w);
    ((ushort4*)Xbf)[i] = o;
  } else {
    int j = id - 8192;                    // 0..3071
    int g = j >> 10;
    const float* W = (g == 0) ? Wq : (g == 1) ? Wk : Wv;
    float scale = (g == 0) ? 0.03125f : 1.0f;   // fold 1/sqrt(1024) into W_q
    int i = (j & 1023) * 256 + threadIdx.x;
    float4 v = ((const float4*)W)[i];
    ushort4 o;
    o.x = f2bf(v.x * scale); o.y = f2bf(v.y * scale);
    o.z = f2bf(v.z * scale); o.w = f2bf(v.w * scale);
    ((ushort4*)(Wbf + (size_t)g * 1048576))[i] = o;
  }
}

// ---------------- common helpers ----------------
// LDS rows are 64 bf16 = 128B; XOR swizzle byte ^= (row&7)<<4; inverse applied
// to the global SOURCE slot (global_load_lds writes linearly).

__device__ __forceinline__ void gll16(const void* g, void* l) {
  __builtin_amdgcn_global_load_lds((const __attribute__((address_space(1))) void*)g,
                                   (__attribute__((address_space(3))) void*)l, 16, 0, 0);
}

__device__ __forceinline__ bf16x8 frag_ld(const char* lds, int row, int kbyte) {
  int bo = row * 128 + kbyte;
  bo ^= (row & 7) << 4;
  return *(const bf16x8*)(lds + bo);
}

#define VM_WAIT8() asm volatile("s_waitcnt vmcnt(8)" ::: "memory")
#define VM_WAIT6() asm volatile("s_waitcnt vmcnt(6)" ::: "memory")
#define VM_WAIT0() asm volatile("s_waitcnt vmcnt(0)" ::: "memory")
#define RAW_BAR()  asm volatile("s_barrier" ::: "memory")

// ---------------- staging helpers ----------------
__device__ __forceinline__ void stage_tile(const uint16_t* __restrict__ g, int ld,
                                           int t, char* lds) {
#pragma unroll
  for (int c = 0; c < 4; ++c) {
    int L = c * 4096 + t * 16;
    int row = L >> 7;
    int slot = (t & 7) ^ (row & 7);
    gll16((const void*)(g + (size_t)row * ld + slot * 8), (void*)(lds + L));
  }
}

__device__ __forceinline__ void stage_btile(const uint16_t* __restrict__ g, int ld,
                                            int t, char* lds) {
#pragma unroll
  for (int c = 0; c < 2; ++c) {
    int L = c * 4096 + t * 16;
    int row = L >> 7;
    int slot = (t & 7) ^ (row & 7);
    gll16((const void*)(g + (size_t)row * ld + slot * 8), (void*)(lds + L));
  }
}

// ---------------- 128^2 GEMM core: 2-deep counted-vmcnt pipeline -------------
// Ledger (8 loads/thread per tile = A4 + B4, uniform issue order across threads):
//   prologue: stage(0), stage(1)                      -> 16 loads outstanding
//   tile t entry: vmcnt(8) retires exactly stage(t); barrier => LDS visible
//   post-compute barrier => all reads of buf[t&1] done; then stage(t+2) -> WAR safe
// Proven optimum for k_qkv: 61.6us across R5/R8/R9/R11 (R12's half-tile = 69).
__device__ __forceinline__ void gemm_loop(const uint16_t* __restrict__ A, int lda,
                                          const uint16_t* __restrict__ Bm, int ldb,
                                          int ksteps, char* lds, f32x4 acc[4][4]) {
  char* lA0 = lds;          char* lA1 = lds + 16384;
  char* lB0 = lds + 32768;  char* lB1 = lds + 49152;
  const int t = threadIdx.x;
  const int lane = t & 63;
  const int wm = (t >> 6) & 1;
  const int wn = t >> 7;
  const int frow = lane & 15;
  const int fk16 = (lane >> 4) * 16;

  stage_tile(A,      lda, t, lA0); stage_tile(Bm,      ldb, t, lB0);
  if (ksteps > 1) { stage_tile(A + 64, lda, t, lA1); stage_tile(Bm + 64, ldb, t, lB1); }

  for (int kt = 0; kt < ksteps; ++kt) {
    if (kt == ksteps - 1) { VM_WAIT0(); } else { VM_WAIT8(); }
    RAW_BAR();
    const char* cA = (kt & 1) ? lA1 : lA0;
    const char* cB = (kt & 1) ? lB1 : lB0;
#pragma unroll
    for (int ki = 0; ki < 2; ++ki) {
      bf16x8 av[4], bv[4];
#pragma unroll
      for (int mi = 0; mi < 4; ++mi)
        av[mi] = frag_ld(cA, wm * 64 + mi * 16 + frow, ki * 64 + fk16);
#pragma unroll
      for (int ni = 0; ni < 4; ++ni)
        bv[ni] = frag_ld(cB, wn * 64 + ni * 16 + frow, ki * 64 + fk16);
      __builtin_amdgcn_s_setprio(1);
#pragma unroll
      for (int mi = 0; mi < 4; ++mi)
#pragma unroll
        for (int ni = 0; ni < 4; ++ni)
          acc[mi][ni] = __builtin_amdgcn_mfma_f32_16x16x32_bf16(av[mi], bv[ni],
                                                                acc[mi][ni], 0, 0, 0);
      __builtin_amdgcn_s_setprio(0);
    }
    RAW_BAR();
    if (kt + 2 < ksteps) {
      stage_tile(A  + (kt + 2) * 64, lda, t, (kt & 1) ? lA1 : lA0);
      stage_tile(Bm + (kt + 2) * 64, ldb, t, (kt & 1) ? lB1 : lB0);
    }
  }
}

// ---------------- 128x64 half-tile GEMM core: vmcnt(6), 48KB LDS, 3 blk/CU ---
// Same ledger with 6 loads/K-tile. Proven in k_scores (R8+) and k_pv (R12:
// PV makespan -4us; do NOT use for k_qkv — R12 showed +7.4us there).
__device__ __forceinline__ void gemm_loop_h(const uint16_t* __restrict__ A, int lda,
                                            const uint16_t* __restrict__ Bm, int ldb,
                                            int ksteps, char* lds, f32x4 acc[4][2]) {
  char* lA0 = lds;          char* lA1 = lds + 16384;
  char* lB0 = lds + 32768;  char* lB1 = lds + 40960;
  const int t = threadIdx.x;
  const int lane = t & 63;
  const int wm = (t >> 6) & 1;                  // 64-row strip
  const int wn = t >> 7;                        // 32-col strip (0..1)
  const int frow = lane & 15;
  const int fk16 = (lane >> 4) * 16;

  stage_tile(A, lda, t, lA0); stage_btile(Bm, ldb, t, lB0);
  if (ksteps > 1) { stage_tile(A + 64, lda, t, lA1); stage_btile(Bm + 64, ldb, t, lB1); }

  for (int kt = 0; kt < ksteps; ++kt) {
    if (kt == ksteps - 1) { VM_WAIT0(); } else { VM_WAIT6(); }
    RAW_BAR();
    const char* cA = (kt & 1) ? lA1 : lA0;
    const char* cB = (kt & 1) ? lB1 : lB0;
#pragma unroll
    for (int ki = 0; ki < 2; ++ki) {
      bf16x8 av[4], bv[2];
#pragma unroll
      for (int mi = 0; mi < 4; ++mi)
        av[mi] = frag_ld(cA, wm * 64 + mi * 16 + frow, ki * 64 + fk16);
#pragma unroll
      for (int ni = 0; ni < 2; ++ni)
        bv[ni] = frag_ld(cB, wn * 32 + ni * 16 + frow, ki * 64 + fk16);
      __builtin_amdgcn_s_setprio(1);
#pragma unroll
      for (int mi = 0; mi < 4; ++mi)
#pragma unroll
        for (int ni = 0; ni < 2; ++ni)
          acc[mi][ni] = __builtin_amdgcn_mfma_f32_16x16x32_bf16(av[mi], bv[ni],
                                                                acc[mi][ni], 0, 0, 0);
      __builtin_amdgcn_s_setprio(0);
    }
    RAW_BAR();
    if (kt + 2 < ksteps) {
      stage_tile (A  + (kt + 2) * 64, lda, t, (kt & 1) ? lA1 : lA0);
      stage_btile(Bm + (kt + 2) * 64, ldb, t, (kt & 1) ? lB1 : lB0);
    }
  }
}

// ---------------- QKV projection: fused 8192x3072, 128^2 tiles, 2 blocks/CU --
// Grid 1536 = 64 m x 24 n, m-FASTEST, no swizzle: id mod 8 = XCD and 64*nt
// mod 8 == 0 -> each XCD only touches m-tiles with mt mod 8 == xcd: X slice
// stays L2-resident (proven: FETCH 47MB vs 200MB swizzled).
__global__ __launch_bounds__(256) void k_qkv(const uint16_t* __restrict__ Xbf,
                                             const uint16_t* __restrict__ Wbf,
                                             uint16_t* __restrict__ Qb,
                                             uint16_t* __restrict__ Kb,
                                             uint16_t* __restrict__ Vt) {
  __shared__ __align__(16) char lds[65536];
  int id = blockIdx.x;
  const int mt = id & 63, nt = id >> 6;
  const int m0 = mt * 128, n0 = nt * 128;
  const int g = n0 >> 10, ncol = n0 & 1023;

  f32x4 acc[4][4];
#pragma unroll
  for (int i = 0; i < 4; ++i)
#pragma unroll
    for (int j = 0; j < 4; ++j) acc[i][j] = (f32x4){0.f, 0.f, 0.f, 0.f};

  const uint16_t* A  = Xbf + (size_t)m0 * DIM;
  const uint16_t* Bm = Wbf + (size_t)n0 * DIM;  // Wbf as [3072][1024]
  gemm_loop(A, DIM, Bm, DIM, DIM / 64, lds, acc);

  const int lane = threadIdx.x & 63;
  const int wm = (threadIdx.x >> 6) & 1, wn = threadIdx.x >> 7;
  const int rbase = wm * 64 + (lane >> 4) * 4;  // C row = (lane>>4)*4 + reg
  const int cbase = wn * 64 + (lane & 15);      // C col = lane&15

  if (g < 2) {
    uint16_t* out = (g == 0) ? Qb : Kb;
#pragma unroll
    for (int mi = 0; mi < 4; ++mi)
#pragma unroll
      for (int ni = 0; ni < 4; ++ni) {
        int c = ncol + cbase + ni * 16;
#pragma unroll
        for (int r = 0; r < 4; ++r) {
          int m = m0 + rbase + mi * 16 + r;
          out[(size_t)m * DIM + c] = f2bf(acc[mi][ni][r]);
        }
      }
  } else {
    // write V transposed: Vt[b][e][s]
    const int b = m0 >> 11, sl = m0 & 2047;
#pragma unroll
    for (int mi = 0; mi < 4; ++mi)
#pragma unroll
      for (int ni = 0; ni < 4; ++ni) {
        int e = ncol + cbase + ni * 16;
        int s = sl + rbase + mi * 16;
        ushort4 o;
        o.x = f2bf(acc[mi][ni][0]); o.y = f2bf(acc[mi][ni][1]);
        o.z = f2bf(acc[mi][ni][2]); o.w = f2bf(acc[mi][ni][3]);
        *(ushort4*)(Vt + ((size_t)b * DIM + e) * SEQ + s) = o;
      }
  }
}

// ---------------- causal scores: Sc = Q K^T, 128x64 half-tile jobs, fp16 -----
// XCD-aware decode: id mod 8 = p = qt-PAIR index {p, 15-p} (pairs sum to 34
// half-jobs -> all 8 XCDs get exactly 136 jobs). Within an XCD, b-major so the
// live Q working set is one batch's panels (~512KB, L2-resident).
__global__ __launch_bounds__(256) void k_scores(const uint16_t* __restrict__ Qb,
                                                const uint16_t* __restrict__ Kb,
                                                __half* __restrict__ Sc) {
  __shared__ __align__(16) char lds[49152];
  int id = blockIdx.x;                // 0..1087
  int p = id & 7;                     // XCD residue = qt-pair
  int w = id >> 3;                    // 0..135
  int b = w / 34;
  int l = w % 34;
  int thr = (p + 1) * 2;
  int qt, hk;
  if (l < thr) { qt = p;      hk = l; }
  else         { qt = 15 - p; hk = l - thr; }
  int kt = hk >> 1, nh = hk & 1;

  f32x4 acc[4][2];
#pragma unroll
  for (int i = 0; i < 4; ++i)
#pragma unroll
    for (int jj = 0; jj < 2; ++jj) acc[i][jj] = (f32x4){0.f, 0.f, 0.f, 0.f};

  const uint16_t* A  = Qb + ((size_t)b * SEQ + qt * 128) * DIM;
  const uint16_t* Bm = Kb + ((size_t)b * SEQ + kt * 128 + nh * 64) * DIM;
  gemm_loop_h(A, DIM, Bm, DIM, DIM / 64, lds, acc);

  const int lane = threadIdx.x & 63;
  const int wm = (threadIdx.x >> 6) & 1, wn = threadIdx.x >> 7;
  const int rbase = qt * 128 + wm * 64 + (lane >> 4) * 4;
  const int cbase = kt * 128 + nh * 64 + wn * 32 + (lane & 15);
  __half* out = Sc + (size_t)b * SEQ * SEQ;
#pragma unroll
  for (int mi = 0; mi < 4; ++mi)
#pragma unroll
    for (int ni = 0; ni < 2; ++ni) {
      int c = cbase + ni * 16;
#pragma unroll
      for (int r = 0; r < 4; ++r)
        out[(size_t)(rbase + mi * 16 + r) * SEQ + c] = __float2half(acc[mi][ni][r]);
    }
}

// ---------------- row softmax: one WAVE per row, fp16 row in registers -------
struct h4 { __half2 a, b; };          // 8 bytes = 4 halves

__global__ __launch_bounds__(256) void k_softmax(const __half* __restrict__ Sc,
                                                 uint16_t* __restrict__ P) {
  int gid = blockIdx.x * 4 + (threadIdx.x >> 6);
  int lane = threadIdx.x & 63;
  int b = gid >> 11, q = gid & 2047;
  const __half* srow = Sc + ((size_t)b * SEQ + q) * SEQ;
  uint16_t* prow = P + ((size_t)b * SEQ + q) * SEQ;
  int nv = q + 1;
  int kpad = ((q >> 7) + 1) << 7;     // PV reads exactly [0, kpad)
  int niter = (kpad + 255) >> 8;      // 256 halves per wave-iter

  float4 v[8];
  const h4* src = (const h4*)srow;
#pragma unroll
  for (int i = 0; i < 8; ++i) {
    if (i < niter) {
      int idx = lane + (i << 6);
      h4 raw = src[idx];
      float2 fa = __half22float2(raw.a), fb = __half22float2(raw.b);
      int k0 = idx << 2;
      float4 x;
      x.x = (k0 + 0 < nv) ? fa.x : -1e38f;
      x.y = (k0 + 1 < nv) ? fa.y : -1e38f;
      x.z = (k0 + 2 < nv) ? fb.x : -1e38f;
      x.w = (k0 + 3 < nv) ? fb.y : -1e38f;
      v[i] = x;
    } else {
      v[i] = make_float4(-1e38f, -1e38f, -1e38f, -1e38f);
    }
  }
  float m = -1e38f;
#pragma unroll
  for (int i = 0; i < 8; ++i)
    m = fmaxf(m, fmaxf(fmaxf(v[i].x, v[i].y), fmaxf(v[i].z, v[i].w)));
#pragma unroll
  for (int o = 32; o > 0; o >>= 1) m = fmaxf(m, __shfl_xor(m, o));

  float s = 0.f;
#pragma unroll
  for (int i = 0; i < 8; ++i) {
    v[i].x = __expf(v[i].x - m); v[i].y = __expf(v[i].y - m);
    v[i].z = __expf(v[i].z - m); v[i].w = __expf(v[i].w - m);
    s += v[i].x + v[i].y + v[i].z + v[i].w;
  }
#pragma unroll
  for (int o = 32; o > 0; o >>= 1) s += __shfl_xor(s, o);
  float inv = 1.0f / s;

  ushort4* dst = (ushort4*)prow;
#pragma unroll
  for (int i = 0; i < 8; ++i) {
    if (i < niter) {
      int idx = lane + (i << 6);
      if ((idx << 2) < kpad) {
        ushort4 o;
        o.x = f2bf(v[i].x * inv); o.y = f2bf(v[i].y * inv);
        o.z = f2bf(v[i].z * inv); o.w = f2bf(v[i].w * inv);
        dst[idx] = o;
      }
    }
  }
}

// ---------------- PV: O = P V, 128x64 half-tile jobs, 3 blk/CU ---------------
// 1024 jobs = 4b x 16qt x 16et-strips. id mod 8 = b*2+parity -> each XCD hosts
// ONE batch's Vt (4MB, L2-resident) and the 16 et-blocks sharing a P panel sit
// on the SAME XCD. qt = 14-2a+parity -> longest K-loops dispatch FIRST.
// R12 measured: non-qkv makespan 81.4 -> 77.3us with this regrid.
__global__ __launch_bounds__(256) void k_pv(const uint16_t* __restrict__ P,
                                            const uint16_t* __restrict__ Vt,
                                            float* __restrict__ O) {
  __shared__ __align__(16) char lds[49152];
  int id = blockIdx.x;                // 0..1023
  int lo = id & 7;
  int b = lo >> 1, parity = lo & 1;
  int w = id >> 3;                    // 0..127 = a*16 + et
  int a = w >> 4, et = w & 15;
  int qt = 14 - 2 * a + parity;       // a=0 -> qt 15/14 (longest first)

  f32x4 acc[4][2];
#pragma unroll
  for (int i = 0; i < 4; ++i)
#pragma unroll
    for (int j = 0; j < 2; ++j) acc[i][j] = (f32x4){0.f, 0.f, 0.f, 0.f};

  const uint16_t* A = P + (size_t)b * SEQ * SEQ + (size_t)qt * 128 * SEQ;
  const uint16_t* Bm = Vt + (size_t)b * DIM * SEQ + (size_t)et * 64 * SEQ;
  gemm_loop_h(A, SEQ, Bm, SEQ, (qt + 1) * 2, lds, acc);

  const int lane = threadIdx.x & 63;
  const int wm = (threadIdx.x >> 6) & 1, wn = threadIdx.x >> 7;
  const int rbase = qt * 128 + wm * 64 + (lane >> 4) * 4;
  const int cbase = et * 64 + wn * 32 + (lane & 15);
  float* out = O + (size_t)b * SEQ * DIM;
#pragma unroll
  for (int mi = 0; mi < 4; ++mi)
#pragma unroll
    for (int ni = 0; ni < 2; ++ni) {
      int c = cbase + ni * 16;
#pragma unroll
      for (int r = 0; r < 4; ++r)
        out[(size_t)(rbase + mi * 16 + r) * DIM + c] = acc[mi][ni][r];
    }
}

extern "C" void kernel_launch(void* const* d_in, const int* in_sizes, int n_in,
                              void* d_out, int out_size, void* d_ws, size_t ws_size,
                              hipStream_t stream) {
  const float* X  = (const float*)d_in[0];
  const float* Wq = (const float*)d_in[1];
  const float* Wk = (const float*)d_in[2];
  const float* Wv = (const float*)d_in[3];
  char* ws = (char*)d_ws;
  uint16_t* Xbf = (uint16_t*)(ws + OFF_XBF);
  uint16_t* Wbf = (uint16_t*)(ws + OFF_WBF);
  uint16_t* Qb  = (uint16_t*)(ws + OFF_Q);
  uint16_t* Kb  = (uint16_t*)(ws + OFF_K);
  uint16_t* Vt  = (uint16_t*)(ws + OFF_VT);
  __half*   Sc  = (__half*)(ws + OFF_SC);
  uint16_t* P   = (uint16_t*)(ws + OFF_P);
  float*    O   = (float*)d_out;

  k_convert<<<11264, 256, 0, stream>>>(X, Wq, Wk, Wv, Xbf, Wbf);
  k_qkv<<<1536, 256, 0, stream>>>(Xbf, Wbf, Qb, Kb, Vt);
  k_scores<<<1088, 256, 0, stream>>>(Qb, Kb, Sc);
  k_softmax<<<2048, 256, 0, stream>>>(Sc, P);
  k_pv<<<1024, 256, 0, stream>>>(P, Vt, O);
}